// Round 3
// baseline (283.549 us; speedup 1.0000x reference)
//
#include <hip/hip_runtime.h>
#include <hip/hip_bf16.h>

#define NFREQ 512
#define KDIM  1024   // 2*NFREQ combined (magn || phase)
#define CDIM  1024   // NFFT output channels
#define TDIM  4096
#define BATCH 8
#define NT    16     // K-tiles of 64

typedef __bf16 bf16;
typedef __attribute__((ext_vector_type(8))) __bf16 bf16x8;
typedef __attribute__((ext_vector_type(4))) float f32x4;

__device__ __forceinline__ void gload_lds16(const bf16* g, void* l) {
    __builtin_amdgcn_global_load_lds(
        (const __attribute__((address_space(1))) void*)g,
        (__attribute__((address_space(3))) void*)l, 16, 0, 0);
}

// ---------------- prep: combined, pre-scaled kernel matrix ----------------
__global__ __launch_bounds__(256) void prep_kc(const float* __restrict__ rk,
                                               const float* __restrict__ ik,
                                               bf16* __restrict__ Kc) {
    int idx = blockIdx.x * 256 + threadIdx.x;
    int c = idx >> 10;
    int k = idx & 1023;
    float v = (k < NFREQ) ? rk[c * NFREQ + k] : -ik[c * NFREQ + (k - NFREQ)];
    Kc[idx] = (bf16)(v * (1.0f / 1024.0f));
}

// ---------------- transpose: [b][f][t] f32 -> Xt[b][t][k] bf16 ----------------
__global__ __launch_bounds__(256) void transpose_kernel(const float* __restrict__ magn,
                                                        const float* __restrict__ phase,
                                                        bf16* __restrict__ Xt) {
    __shared__ bf16 tile[64][68];
    const int tid = threadIdx.x;
    const int tt  = blockIdx.x & 63;
    const int ft  = blockIdx.x >> 6;
    const int b   = blockIdx.y;
    const int src = blockIdx.z;
    const float* in = src ? phase : magn;
    const int f0 = ft * 64, t0 = tt * 64;
    const size_t base = (size_t)b * NFREQ * TDIM;

    const int r0 = tid >> 4;
    const int c4 = (tid & 15) * 4;
#pragma unroll
    for (int i = 0; i < 4; i++) {
        int r = r0 + i * 16;
        const float4 v = *(const float4*)&in[base + (size_t)(f0 + r) * TDIM + t0 + c4];
        tile[r][c4 + 0] = (bf16)v.x;
        tile[r][c4 + 1] = (bf16)v.y;
        tile[r][c4 + 2] = (bf16)v.z;
        tile[r][c4 + 3] = (bf16)v.w;
    }
    __syncthreads();
    const int kbase = src * NFREQ + f0;
#pragma unroll
    for (int i = 0; i < 2; i++) {
        int ch = tid + 256 * i;
        int tr = ch >> 3;
        int c8 = (ch & 7) * 8;
        bf16x8 o;
#pragma unroll
        for (int j = 0; j < 8; j++) o[j] = tile[c8 + j][tr];
        *(bf16x8*)&Xt[((size_t)b * TDIM + t0 + tr) * KDIM + kbase + c8] = o;
    }
}

// ---------------- GEMM: 256x256 tile, BK=64, 8-phase counted-vmcnt ----------------
// Persistent: 256 WGs, each does a bm-pair (2 tiles, same bn, same batch).
// out[b][c][t] = sum_k Kc[c][k] * Xt[b*TDIM+t][k]
__global__ __launch_bounds__(512, 2) void gemm8(const bf16* __restrict__ Kc,
                                                const bf16* __restrict__ Xt,
                                                float* __restrict__ out) {
    extern __shared__ __align__(16) char smem[];   // 128 KB: [buf][A 32K | B 32K]

    const int tid = threadIdx.x;
    const int w = tid >> 6;          // wave 0..7
    const int l = tid & 63;

    // XCD-locality decode: batch = g&7 (one batch per XCD, dispatch round-robin),
    // bn = (g>>3)&15, bm-pair = g>>7.  Pair shares bn -> B panel L2-reused.
    const int g   = blockIdx.x;
    const int b   = g & 7;
    const int s   = g >> 3;
    const int bn  = s & 15;
    const int bmp = s >> 4;          // 0..1

    const bf16* Bbase = Xt + ((size_t)b * TDIM + bn * 256) * KDIM;

    // staging geometry
    const int srow   = ((w >> 2) * 128) + ((w & 3) * 8);
    const int ssub   = l >> 3;                    // 0..7 row within wave chunk
    const int scol   = ((l & 7) ^ ssub) * 8;      // inverse-swizzled source col (elems)

    // fragment-read geometry
    const int wr = w >> 2;           // 0..1 (M)
    const int wc = w & 3;            // 0..3 (N)
    const int fr = l & 15;
    const int l16 = l >> 4;          // 0..3
    const int fx = fr & 7;

    f32x4 acc[8][4];

#define STAGE_A(curb, q, kt) \
    gload_lds16(Ab + (size_t)(srow + (q)*32 + ssub) * KDIM + (kt)*64 + scol, \
                smem + (curb)*65536 + (srow + (q)*32) * 128)
#define STAGE_B(curb, q, kt) \
    gload_lds16(Bbase + (size_t)(srow + (q)*32 + ssub) * KDIM + (kt)*64 + scol, \
                smem + (curb)*65536 + 32768 + (srow + (q)*32) * 128)

    for (int ti = 0; ti < 2; ++ti) {
        const int bm = bmp * 2 + ti;
        const bf16* Ab = Kc + (size_t)(bm * 256) * KDIM;

#pragma unroll
        for (int m = 0; m < 8; m++)
#pragma unroll
            for (int n = 0; n < 4; n++)
                acc[m][n] = (f32x4){0.f, 0.f, 0.f, 0.f};

        // prologue: tile0 fully into buf0; tile1 A-q0..2 into buf1
        // (on ti=1 these loads are issued BEFORE the vmcnt(3) that will also
        //  drain ti=0's epilogue stores -> store latency overlaps load issue)
#pragma unroll
        for (int q = 0; q < 4; q++) STAGE_A(0, q, 0);
#pragma unroll
        for (int q = 0; q < 4; q++) STAGE_B(0, q, 0);
        STAGE_A(1, 0, 1); STAGE_A(1, 1, 1); STAGE_A(1, 2, 1);
        asm volatile("s_waitcnt vmcnt(3)" ::: "memory");
        __builtin_amdgcn_s_barrier();
        __builtin_amdgcn_sched_barrier(0);

        for (int v = 0; v < NT; ++v) {
            const int cur = v & 1;
            const char* At = smem + cur * 65536;
            const char* Bt = At + 32768;
            bf16x8 bfr[4][2];

#pragma unroll
            for (int p = 0; p < 4; p++) {
                bf16x8 afr[2][2];
#pragma unroll
                for (int mi = 0; mi < 2; mi++)
#pragma unroll
                    for (int kk = 0; kk < 2; kk++) {
                        const int r = wr * 128 + (p * 2 + mi) * 16 + fr;
                        const int off = r * 128 + (((kk * 4 + l16) ^ fx) * 16);
                        afr[mi][kk] = *(const bf16x8*)(At + off);
                    }
                if (p == 0) {
#pragma unroll
                    for (int n = 0; n < 4; n++)
#pragma unroll
                        for (int kk = 0; kk < 2; kk++) {
                            const int r = wc * 64 + n * 16 + fr;
                            const int off = r * 128 + (((kk * 4 + l16) ^ fx) * 16);
                            bfr[n][kk] = *(const bf16x8*)(Bt + off);
                        }
                }

                // stage issues (regions dead since previous closing barrier)
                if (p == 0) {
                    if (v + 1 < NT) {
                        const int nc = cur ^ 1;
                        STAGE_A(nc, 3, v + 1);
                        STAGE_B(nc, 0, v + 1); STAGE_B(nc, 1, v + 1);
                        STAGE_B(nc, 2, v + 1); STAGE_B(nc, 3, v + 1);
                    }
                } else {
                    if (v + 2 < NT) STAGE_A(cur, p - 1, v + 2);
                }

                __builtin_amdgcn_s_barrier();
                __builtin_amdgcn_s_setprio(1);
#pragma unroll
                for (int mi = 0; mi < 2; mi++)
#pragma unroll
                    for (int n = 0; n < 4; n++)
#pragma unroll
                        for (int kk = 0; kk < 2; kk++)
                            acc[p * 2 + mi][n] = __builtin_amdgcn_mfma_f32_16x16x32_bf16(
                                afr[mi][kk], bfr[n][kk], acc[p * 2 + mi][n], 0, 0, 0);
                __builtin_amdgcn_s_setprio(0);
                if (p == 3) {
                    if (v < NT - 2) { asm volatile("s_waitcnt vmcnt(3)" ::: "memory"); }
                    else            { asm volatile("s_waitcnt vmcnt(0)" ::: "memory"); }
                }
                __builtin_amdgcn_s_barrier();
                __builtin_amdgcn_sched_barrier(0);
            }
        }

        // epilogue: C/D layout col = lane&15, row = (lane>>4)*4 + j
        {
            const int cr = l16 * 4;
            const int cc = fr;
            float* obase = out + ((size_t)b * CDIM + bm * 256 + wr * 128) * TDIM
                               + bn * 256 + wc * 64;
#pragma unroll
            for (int m = 0; m < 8; m++)
#pragma unroll
                for (int n = 0; n < 4; n++)
#pragma unroll
                    for (int j = 0; j < 4; j++)
                        obase[(size_t)(m * 16 + cr + j) * TDIM + n * 16 + cc] = acc[m][n][j];
        }
    }
#undef STAGE_A
#undef STAGE_B
}

// ---------------- fallback (ws too small): naive f32 ----------------
__global__ __launch_bounds__(256) void naive_kernel(const float* __restrict__ m,
                                                    const float* __restrict__ p,
                                                    const float* __restrict__ rk,
                                                    const float* __restrict__ ik,
                                                    float* __restrict__ out) {
    size_t idx = (size_t)blockIdx.x * 256 + threadIdx.x;
    int t = idx & 4095;
    size_t r = idx >> 12;
    int c = (int)(r & 1023);
    int b = (int)(r >> 10);
    float acc = 0.f;
    for (int f = 0; f < NFREQ; f++) {
        acc += rk[c * NFREQ + f] * m[((size_t)b * NFREQ + f) * TDIM + t]
             - ik[c * NFREQ + f] * p[((size_t)b * NFREQ + f) * TDIM + t];
    }
    out[idx] = acc * (1.0f / 1024.0f);
}

extern "C" void kernel_launch(void* const* d_in, const int* in_sizes, int n_in,
                              void* d_out, int out_size, void* d_ws, size_t ws_size,
                              hipStream_t stream) {
    const float* magn  = (const float*)d_in[0];
    const float* phase = (const float*)d_in[1];
    const float* rk    = (const float*)d_in[2];
    const float* ik    = (const float*)d_in[3];
    float* out = (float*)d_out;

    const size_t kc_bytes = (size_t)CDIM * KDIM * sizeof(bf16);          // 2 MB
    const size_t xt_bytes = (size_t)BATCH * TDIM * KDIM * sizeof(bf16);  // 64 MB
    if (ws_size < kc_bytes + xt_bytes) {
        naive_kernel<<<(CDIM * TDIM * BATCH) / 256, 256, 0, stream>>>(magn, phase, rk, ik, out);
        return;
    }

    bf16* Kc = (bf16*)d_ws;
    bf16* Xt = (bf16*)((char*)d_ws + kc_bytes);

    (void)hipFuncSetAttribute((const void*)gemm8,
                              hipFuncAttributeMaxDynamicSharedMemorySize, 131072);

    prep_kc<<<(CDIM * KDIM) / 256, 256, 0, stream>>>(rk, ik, Kc);
    transpose_kernel<<<dim3(512, BATCH, 2), 256, 0, stream>>>(magn, phase, Xt);
    gemm8<<<dim3(256), 512, 131072, stream>>>(Kc, Xt, out);
}

// Round 4
// 121.628 us; speedup vs baseline: 2.3313x; 2.3313x over previous
//
#include <hip/hip_runtime.h>
#include <hip/hip_bf16.h>

#define NFREQ 512
#define KDIM  1024   // 2*NFREQ combined (magn || phase)
#define CDIM  1024   // NFFT output channels
#define TDIM  4096
#define BATCH 8
#define NT    16     // K-tiles of 64

typedef __bf16 bf16;
typedef __attribute__((ext_vector_type(8))) __bf16 bf16x8;
typedef __attribute__((ext_vector_type(4))) float f32x4;

__device__ __forceinline__ void gload_lds16(const bf16* g, void* l) {
    __builtin_amdgcn_global_load_lds(
        (const __attribute__((address_space(1))) void*)g,
        (__attribute__((address_space(3))) void*)l, 16, 0, 0);
}

// ---------------- prep: combined, pre-scaled kernel matrix ----------------
__global__ __launch_bounds__(256) void prep_kc(const float* __restrict__ rk,
                                               const float* __restrict__ ik,
                                               bf16* __restrict__ Kc) {
    int idx = blockIdx.x * 256 + threadIdx.x;
    int c = idx >> 10;
    int k = idx & 1023;
    float v = (k < NFREQ) ? rk[c * NFREQ + k] : -ik[c * NFREQ + (k - NFREQ)];
    Kc[idx] = (bf16)(v * (1.0f / 1024.0f));
}

// ---------------- transpose: [b][f][t] f32 -> Xt[b][t][k] bf16 ----------------
__global__ __launch_bounds__(256) void transpose_kernel(const float* __restrict__ magn,
                                                        const float* __restrict__ phase,
                                                        bf16* __restrict__ Xt) {
    __shared__ bf16 tile[64][68];
    const int tid = threadIdx.x;
    const int tt  = blockIdx.x & 63;
    const int ft  = blockIdx.x >> 6;
    const int b   = blockIdx.y;
    const int src = blockIdx.z;
    const float* in = src ? phase : magn;
    const int f0 = ft * 64, t0 = tt * 64;
    const size_t base = (size_t)b * NFREQ * TDIM;

    const int r0 = tid >> 4;
    const int c4 = (tid & 15) * 4;
#pragma unroll
    for (int i = 0; i < 4; i++) {
        int r = r0 + i * 16;
        const float4 v = *(const float4*)&in[base + (size_t)(f0 + r) * TDIM + t0 + c4];
        tile[r][c4 + 0] = (bf16)v.x;
        tile[r][c4 + 1] = (bf16)v.y;
        tile[r][c4 + 2] = (bf16)v.z;
        tile[r][c4 + 3] = (bf16)v.w;
    }
    __syncthreads();
    const int kbase = src * NFREQ + f0;
#pragma unroll
    for (int i = 0; i < 2; i++) {
        int ch = tid + 256 * i;
        int tr = ch >> 3;
        int c8 = (ch & 7) * 8;
        bf16x8 o;
#pragma unroll
        for (int j = 0; j < 8; j++) o[j] = tile[c8 + j][tr];
        *(bf16x8*)&Xt[((size_t)b * TDIM + t0 + tr) * KDIM + kbase + c8] = o;
    }
}

// ---------------- GEMM: 256x256 tile, BK=64, 8-phase counted-vmcnt ----------------
// out[b][c][t] = sum_k Kc[c][k] * Xt[b*TDIM+t][k]
// Decode: bm = x>>4, bn = x&15, b = y. With x-fastest dispatch and
// round-robin block->XCD (gid%8 = x%8), the 4 bm-sharers of a (b,bn) B-panel
// (x = bn, bn+16, bn+32, bn+48) all land on XCD bn%8 -> B chunks fetched from
// HBM once, 3x L2 hits (lockstep K).
__global__ __launch_bounds__(512, 2) void gemm8(const bf16* __restrict__ Kc,
                                                const bf16* __restrict__ Xt,
                                                float* __restrict__ out) {
    extern __shared__ __align__(16) char smem[];   // 128 KB: [buf][A 32K | B 32K]

    const int tid = threadIdx.x;
    const int w = tid >> 6;          // wave 0..7
    const int l = tid & 63;

    const int x  = blockIdx.x;
    const int bm = x >> 4;           // 0..3  (c tiles of 256)
    const int bn = x & 15;           // 0..15 (t tiles of 256)
    const int b  = blockIdx.y;

    const bf16* Ab    = Kc + (size_t)(bm * 256) * KDIM;
    const bf16* Bbase = Xt + ((size_t)b * TDIM + bn * 256) * KDIM;

    // staging geometry
    const int srow   = ((w >> 2) * 128) + ((w & 3) * 8);
    const int ssub   = l >> 3;                    // 0..7 row within wave chunk
    const int scol   = ((l & 7) ^ ssub) * 8;      // inverse-swizzled source col (elems)

    // fragment-read geometry
    const int wr = w >> 2;           // 0..1 (M)
    const int wc = w & 3;            // 0..3 (N)
    const int fr = l & 15;
    const int l16 = l >> 4;          // 0..3
    const int fx = fr & 7;

    f32x4 acc[8][4] = {};

#define STAGE_A(curb, q, kt) \
    gload_lds16(Ab + (size_t)(srow + (q)*32 + ssub) * KDIM + (kt)*64 + scol, \
                smem + (curb)*65536 + (srow + (q)*32) * 128)
#define STAGE_B(curb, q, kt) \
    gload_lds16(Bbase + (size_t)(srow + (q)*32 + ssub) * KDIM + (kt)*64 + scol, \
                smem + (curb)*65536 + 32768 + (srow + (q)*32) * 128)

    // prologue: tile0 fully into buf0; tile1 A-q0..2 into buf1
#pragma unroll
    for (int q = 0; q < 4; q++) STAGE_A(0, q, 0);
#pragma unroll
    for (int q = 0; q < 4; q++) STAGE_B(0, q, 0);
    STAGE_A(1, 0, 1); STAGE_A(1, 1, 1); STAGE_A(1, 2, 1);
    asm volatile("s_waitcnt vmcnt(3)" ::: "memory");
    __builtin_amdgcn_s_barrier();
    __builtin_amdgcn_sched_barrier(0);

    for (int v = 0; v < NT; ++v) {
        const int cur = v & 1;
        const char* At = smem + cur * 65536;
        const char* Bt = At + 32768;
        bf16x8 bfr[4][2];

#pragma unroll
        for (int p = 0; p < 4; p++) {
            bf16x8 afr[2][2];
#pragma unroll
            for (int mi = 0; mi < 2; mi++)
#pragma unroll
                for (int kk = 0; kk < 2; kk++) {
                    const int r = wr * 128 + (p * 2 + mi) * 16 + fr;
                    const int off = r * 128 + (((kk * 4 + l16) ^ fx) * 16);
                    afr[mi][kk] = *(const bf16x8*)(At + off);
                }
            if (p == 0) {
#pragma unroll
                for (int n = 0; n < 4; n++)
#pragma unroll
                    for (int kk = 0; kk < 2; kk++) {
                        const int r = wc * 64 + n * 16 + fr;
                        const int off = r * 128 + (((kk * 4 + l16) ^ fx) * 16);
                        bfr[n][kk] = *(const bf16x8*)(Bt + off);
                    }
            }

            // stage issues (regions dead since previous closing barrier)
            if (p == 0) {
                if (v + 1 < NT) {
                    const int nc = cur ^ 1;
                    STAGE_A(nc, 3, v + 1);
                    STAGE_B(nc, 0, v + 1); STAGE_B(nc, 1, v + 1);
                    STAGE_B(nc, 2, v + 1); STAGE_B(nc, 3, v + 1);
                }
            } else {
                if (v + 2 < NT) STAGE_A(cur, p - 1, v + 2);
            }

            __builtin_amdgcn_s_barrier();
            __builtin_amdgcn_s_setprio(1);
#pragma unroll
            for (int mi = 0; mi < 2; mi++)
#pragma unroll
                for (int n = 0; n < 4; n++)
#pragma unroll
                    for (int kk = 0; kk < 2; kk++)
                        acc[p * 2 + mi][n] = __builtin_amdgcn_mfma_f32_16x16x32_bf16(
                            afr[mi][kk], bfr[n][kk], acc[p * 2 + mi][n], 0, 0, 0);
            __builtin_amdgcn_s_setprio(0);
            if (p == 3) {
                if (v < NT - 2) { asm volatile("s_waitcnt vmcnt(3)" ::: "memory"); }
                else            { asm volatile("s_waitcnt vmcnt(0)" ::: "memory"); }
            }
            __builtin_amdgcn_s_barrier();
            __builtin_amdgcn_sched_barrier(0);
        }
    }
#undef STAGE_A
#undef STAGE_B

    // epilogue: C/D layout col = lane&15, row = (lane>>4)*4 + j
    const int cr = l16 * 4;
    const int cc = fr;
    float* obase = out + ((size_t)b * CDIM + bm * 256 + wr * 128) * TDIM + bn * 256 + wc * 64;
#pragma unroll
    for (int m = 0; m < 8; m++)
#pragma unroll
        for (int n = 0; n < 4; n++)
#pragma unroll
            for (int j = 0; j < 4; j++)
                obase[(size_t)(m * 16 + cr + j) * TDIM + n * 16 + cc] = acc[m][n][j];
}

// ---------------- fallback (ws too small): naive f32 ----------------
__global__ __launch_bounds__(256) void naive_kernel(const float* __restrict__ m,
                                                    const float* __restrict__ p,
                                                    const float* __restrict__ rk,
                                                    const float* __restrict__ ik,
                                                    float* __restrict__ out) {
    size_t idx = (size_t)blockIdx.x * 256 + threadIdx.x;
    int t = idx & 4095;
    size_t r = idx >> 12;
    int c = (int)(r & 1023);
    int b = (int)(r >> 10);
    float acc = 0.f;
    for (int f = 0; f < NFREQ; f++) {
        acc += rk[c * NFREQ + f] * m[((size_t)b * NFREQ + f) * TDIM + t]
             - ik[c * NFREQ + f] * p[((size_t)b * NFREQ + f) * TDIM + t];
    }
    out[idx] = acc * (1.0f / 1024.0f);
}

extern "C" void kernel_launch(void* const* d_in, const int* in_sizes, int n_in,
                              void* d_out, int out_size, void* d_ws, size_t ws_size,
                              hipStream_t stream) {
    const float* magn  = (const float*)d_in[0];
    const float* phase = (const float*)d_in[1];
    const float* rk    = (const float*)d_in[2];
    const float* ik    = (const float*)d_in[3];
    float* out = (float*)d_out;

    const size_t kc_bytes = (size_t)CDIM * KDIM * sizeof(bf16);          // 2 MB
    const size_t xt_bytes = (size_t)BATCH * TDIM * KDIM * sizeof(bf16);  // 64 MB
    if (ws_size < kc_bytes + xt_bytes) {
        naive_kernel<<<(CDIM * TDIM * BATCH) / 256, 256, 0, stream>>>(magn, phase, rk, ik, out);
        return;
    }

    bf16* Kc = (bf16*)d_ws;
    bf16* Xt = (bf16*)((char*)d_ws + kc_bytes);

    (void)hipFuncSetAttribute((const void*)gemm8,
                              hipFuncAttributeMaxDynamicSharedMemorySize, 131072);

    prep_kc<<<(CDIM * KDIM) / 256, 256, 0, stream>>>(rk, ik, Kc);
    transpose_kernel<<<dim3(512, BATCH, 2), 256, 0, stream>>>(magn, phase, Xt);
    gemm8<<<dim3(64, BATCH), 512, 131072, stream>>>(Kc, Xt, out);
}